// Round 5
// baseline (282.176 us; speedup 1.0000x reference)
//
#include <hip/hip_runtime.h>

// Problem constants (from reference): B=32, CIN=64, COUT=64, H=W=128, 1x1 conv
#define CIN   64
#define COUT  64
#define HW    16384          // 128*128
#define TPX   256            // pixels per tile (= block threads)
#define NTILE 8              // tiles per block
#define SPAN  (TPX * NTILE)  // 2048 consecutive pixels per block

// ---------------------------------------------------------------------------
// Prep kernel: pack weights to int8 dwords + fold requant params.
// wp[o*16 + k] holds (w[o][4k..4k+3] - wzp[o]) as 4 signed bytes.
// params[o] = { scale_o, bias_o/os + ozp, as_float(sum_ci(w'-wzp)), 0 }
// ---------------------------------------------------------------------------
__global__ void prep_kernel(const int* __restrict__ w,
                            const float* __restrict__ wscale,
                            const int* __restrict__ wzp,
                            const float* __restrict__ bias,
                            const float* __restrict__ is_p,
                            const float* __restrict__ os_p,
                            const int* __restrict__ ozp_p,
                            int* __restrict__ wp,
                            float4* __restrict__ params) {
    int o = threadIdx.x;
    if (o >= COUT) return;
    int zp = wzp[o];
    int sum = 0;
    #pragma unroll
    for (int k = 0; k < 16; ++k) {
        int c0 = w[o * CIN + 4 * k + 0] - zp;
        int c1 = w[o * CIN + 4 * k + 1] - zp;
        int c2 = w[o * CIN + 4 * k + 2] - zp;
        int c3 = w[o * CIN + 4 * k + 3] - zp;
        sum += c0 + c1 + c2 + c3;
        wp[o * 16 + k] = (c0 & 0xff) | ((c1 & 0xff) << 8) |
                         ((c2 & 0xff) << 16) | ((c3 & 0xff) << 24);
    }
    float scale = is_p[0] * wscale[o] / os_p[0];
    float bterm = bias[o] / os_p[0] + (float)ozp_p[0];
    float4 pr;
    pr.x = scale;
    pr.y = bterm;
    pr.z = __int_as_float(sum);
    pr.w = 0.0f;
    params[o] = pr;
}

// ---------------------------------------------------------------------------
// Main kernel: persistent double-buffered pipeline (T3+T4 pattern, downsized).
//
// ROUND-4 POST-MORTEM: async staging + __syncthreads was a CONVOY — the
// compiler's vmcnt(0) drain at the barrier serialized stage and compute,
// HBM read pipe idle during every compute phase -> neutral (82.6 us).
// FIX: 256 blocks (exactly 1/CU), each owns 2048 consecutive pixels of one
// image = 8 tiles of 256 px. Two 64 KB LDS buffers; tile t+1's
// global_load_lds instrs are issued BEFORE waiting on tile t, and the wait
// is a counted `s_waitcnt vmcnt(16)` + RAW s_barrier (no compiler drain),
// so 64 KB/block of reads stay in flight under every compute phase.
//
// vmcnt accounting (per wave, FIFO, in-order): entering iter t the queue is
// [loads(t):16][stores(t-1):<=64]; issuing loads(t+1) appends 16. Waiting
// vmcnt(16) leaves only loads(t+1) outstanding => loads(t) complete (and
// stores drained, harmless). Barrier B1 publishes all waves' LDS writes;
// barrier B2 after compute protects buf reuse (wave's ds_reads completed
// before B2 via data deps). Barrier count is wave-uniform.
//
// Per-block DRAM pattern: each channel row read as 8 sequential 1 KB
// chunks (8 KB runs); out rows written as 1 KB chunks, sequential across
// tiles. LDS gather: bank = tid&31 -> 2 lanes/bank = free (m136).
// ---------------------------------------------------------------------------
__global__ __launch_bounds__(256) void conv_kernel(
    const int* __restrict__ x,
    const int* __restrict__ wp_g,
    const float4* __restrict__ params_g,
    const int* __restrict__ izp_p,
    int* __restrict__ out) {

    __shared__ int    s_x[2][CIN * TPX];  // 2 x 64 KB double buffer
    __shared__ int4   s_wp[COUT * 4];     // 4 KB
    __shared__ float4 s_par[COUT];        // 1 KB   -> 136 KB total, 1 block/CU

    const int tid  = threadIdx.x;        // 0..255
    const int wave = tid >> 6;           // 0..3
    const int lane = tid & 63;

    const int span   = blockIdx.x;       // 0..255
    const int b      = span >> 3;        // image (8 blocks per image)
    const int p_base = (span & 7) * SPAN;

    const int* xb      = x   + b * (CIN  * HW);
    int*       ob_base = out + b * (COUT * HW);

    // ---- weights/params once per block
    s_wp[tid] = ((const int4*)wp_g)[tid];           // 256 int4 = all 4 KB
    if (tid < COUT) s_par[tid] = params_g[tid];
    const int izp_adj = izp_p[0] - 128;             // 0 for reference inputs
    __syncthreads();                                // one-time full drain: fine

    // ---- stage tile t into buffer bi: 16 gload_lds per wave, one channel
    // row each (wave w covers channels 16w..16w+15). Global: lane reads 16 B
    // at row offset lane*16; LDS dest linear base+lane*16 = s_x[bi][c][4l..].
    auto STAGE = [&](int t, int bi) {
        const int p0 = p_base + t * TPX;
        #pragma unroll
        for (int j = 0; j < 16; ++j) {
            const int c = wave * 16 + j;
            const int* gp = xb + c * HW + p0 + lane * 4;   // 1 KB-aligned rows
            __builtin_amdgcn_global_load_lds(
                (const __attribute__((address_space(1))) int*)gp,
                (__attribute__((address_space(3))) int*)&s_x[bi][c * TPX],
                16, 0, 0);
        }
    };

    // ---- compute tile t from buffer bi (round-0's proven body)
    auto COMPUTE = [&](int t, int bi) {
        const int p0 = p_base + t * TPX;
        const int* sx = s_x[bi];

        int px[16];
        #pragma unroll
        for (int cg = 0; cg < 16; ++cg) {
            int v0 = sx[(4 * cg + 0) * TPX + tid];
            int v1 = sx[(4 * cg + 1) * TPX + tid];
            int v2 = sx[(4 * cg + 2) * TPX + tid];
            int v3 = sx[(4 * cg + 3) * TPX + tid];
            // values 0..255 in low byte; (x-128) as int8 == byte XOR 0x80
            px[cg] = (v0 | (v1 << 8) | (v2 << 16) | (v3 << 24)) ^ 0x80808080;
        }

        int* ob = ob_base + p0 + tid;
        #pragma unroll 8
        for (int o = 0; o < COUT; ++o) {
            int4 w0 = s_wp[o * 4 + 0];     // wave-uniform addr -> broadcast
            int4 w1 = s_wp[o * 4 + 1];
            int4 w2 = s_wp[o * 4 + 2];
            int4 w3 = s_wp[o * 4 + 3];
            float4 pr = s_par[o];
            int wsum = __float_as_int(pr.z);
            int acc = -izp_adj * wsum;     // izp correction (0 here)

            acc = __builtin_amdgcn_sdot4(px[0],  w0.x, acc, false);
            acc = __builtin_amdgcn_sdot4(px[1],  w0.y, acc, false);
            acc = __builtin_amdgcn_sdot4(px[2],  w0.z, acc, false);
            acc = __builtin_amdgcn_sdot4(px[3],  w0.w, acc, false);
            acc = __builtin_amdgcn_sdot4(px[4],  w1.x, acc, false);
            acc = __builtin_amdgcn_sdot4(px[5],  w1.y, acc, false);
            acc = __builtin_amdgcn_sdot4(px[6],  w1.z, acc, false);
            acc = __builtin_amdgcn_sdot4(px[7],  w1.w, acc, false);
            acc = __builtin_amdgcn_sdot4(px[8],  w2.x, acc, false);
            acc = __builtin_amdgcn_sdot4(px[9],  w2.y, acc, false);
            acc = __builtin_amdgcn_sdot4(px[10], w2.z, acc, false);
            acc = __builtin_amdgcn_sdot4(px[11], w2.w, acc, false);
            acc = __builtin_amdgcn_sdot4(px[12], w3.x, acc, false);
            acc = __builtin_amdgcn_sdot4(px[13], w3.y, acc, false);
            acc = __builtin_amdgcn_sdot4(px[14], w3.z, acc, false);
            acc = __builtin_amdgcn_sdot4(px[15], w3.w, acc, false);

            float f = fmaf((float)acc, pr.x, pr.y);
            f = rintf(f);                        // v_rndne matches jnp.round
            f = fminf(fmaxf(f, 0.0f), 255.0f);
            __builtin_nontemporal_store((int)f, ob + o * HW);
        }
    };

    // ---- pipeline: prologue + 7 overlapped iters + epilogue
    STAGE(0, 0);
    #pragma unroll 1
    for (int t = 0; t < NTILE - 1; ++t) {
        STAGE(t + 1, (t + 1) & 1);                       // prefetch next tile
        asm volatile("s_waitcnt vmcnt(16)" ::: "memory"); // tile t loads done;
                                                          // prefetch stays in flight
        __builtin_amdgcn_s_barrier();                     // B1: publish LDS
        __builtin_amdgcn_sched_barrier(0);
        COMPUTE(t, t & 1);
        __builtin_amdgcn_s_barrier();                     // B2: buf reuse guard
    }
    asm volatile("s_waitcnt vmcnt(0)" ::: "memory");      // last tile (once)
    __builtin_amdgcn_s_barrier();
    __builtin_amdgcn_sched_barrier(0);
    COMPUTE(NTILE - 1, (NTILE - 1) & 1);
}

extern "C" void kernel_launch(void* const* d_in, const int* in_sizes, int n_in,
                              void* d_out, int out_size, void* d_ws, size_t ws_size,
                              hipStream_t stream) {
    const int*   x      = (const int*)d_in[0];     // [32,64,128,128] int32 (uint8 vals)
    const float* is_p   = (const float*)d_in[1];   // input_scale
    const int*   izp_p  = (const int*)d_in[2];     // input_zero_point
    const int*   w      = (const int*)d_in[3];     // [64,64,1,1] int32
    const float* wscale = (const float*)d_in[4];   // [64]
    const int*   wzp    = (const int*)d_in[5];     // [64]
    const float* bias   = (const float*)d_in[6];   // [64]
    const float* os_p   = (const float*)d_in[7];   // output_scale
    const int*   ozp_p  = (const int*)d_in[8];     // output_zero_point

    int* out = (int*)d_out;

    int*    wp     = (int*)d_ws;                       // 4096 B
    float4* params = (float4*)((char*)d_ws + 4096);    // 1024 B

    prep_kernel<<<1, 64, 0, stream>>>(w, wscale, wzp, bias, is_p, os_p, ozp_p, wp, params);

    // 524288 pixels / 2048 per block = 256 blocks (exactly 1 per CU),
    // 256 threads, 8 double-buffered tiles each
    conv_kernel<<<256, 256, 0, stream>>>(x, wp, params, izp_p, out);
}

// Round 6
// 254.867 us; speedup vs baseline: 1.1072x; 1.1072x over previous
//
#include <hip/hip_runtime.h>

// Problem constants (from reference): B=32, CIN=64, COUT=64, H=W=128, 1x1 conv
#define CIN   64
#define COUT  64
#define HW    16384          // 128*128
#define NPIX  (32 * HW)      // B * H * W = 524288

// ---------------------------------------------------------------------------
// Prep kernel: pack weights to int8 dwords + fold requant params.
// wp[o*16 + k] holds (w[o][4k..4k+3] - wzp[o]) as 4 signed bytes.
// params[o] = { scale_o, bias_o/os + ozp, as_float(sum_ci(w'-wzp)), 0 }
// ---------------------------------------------------------------------------
__global__ void prep_kernel(const int* __restrict__ w,
                            const float* __restrict__ wscale,
                            const int* __restrict__ wzp,
                            const float* __restrict__ bias,
                            const float* __restrict__ is_p,
                            const float* __restrict__ os_p,
                            const int* __restrict__ ozp_p,
                            int* __restrict__ wp,
                            float4* __restrict__ params) {
    int o = threadIdx.x;
    if (o >= COUT) return;
    int zp = wzp[o];
    int sum = 0;
    #pragma unroll
    for (int k = 0; k < 16; ++k) {
        int c0 = w[o * CIN + 4 * k + 0] - zp;
        int c1 = w[o * CIN + 4 * k + 1] - zp;
        int c2 = w[o * CIN + 4 * k + 2] - zp;
        int c3 = w[o * CIN + 4 * k + 3] - zp;
        sum += c0 + c1 + c2 + c3;
        wp[o * 16 + k] = (c0 & 0xff) | ((c1 & 0xff) << 8) |
                         ((c2 & 0xff) << 16) | ((c3 & 0xff) << 24);
    }
    float scale = is_p[0] * wscale[o] / os_p[0];
    float bterm = bias[o] / os_p[0] + (float)ozp_p[0];
    float4 pr;
    pr.x = scale;
    pr.y = bterm;
    pr.z = __int_as_float(sum);
    pr.w = 0.0f;
    params[o] = pr;
}

// ---------------------------------------------------------------------------
// Main kernel: ROUND-0's proven body (83.5 us, the session best), with ONE
// variable changed: 128-thread blocks (4096 of them) instead of 256-thread
// (2048).
//
// RATIONALE (rounds 0-5 post-mortem): time is monotone in resident
// waves/CU (11->83.5us, 8->82.6, 6->95, 3->110). All per-wave-MLP arcs
// failed (allocator spills >88 VGPR; pipelines exposed 1-wave phases).
// Round-0 sits at 11/32 waves per CU despite VGPR=60 and LDS=5KB
// permitting full residency — hypothesis: per-CU workgroup-slot/dispatch
// limit (~8 blocks). Halving the block size doubles the block count per
// CU at identical register/LDS footprint, directly testing (and if right,
// relieving) the slot cap. GATE: occupancy stays ~35% and dur ~83 ->
// hypothesis refuted, pivot to output-split oversubscription.
// ---------------------------------------------------------------------------
__global__ __launch_bounds__(128) void conv_kernel(
    const int* __restrict__ x,
    const int* __restrict__ wp_g,
    const float4* __restrict__ params_g,
    const int* __restrict__ izp_p,
    int* __restrict__ out) {

    __shared__ int4   s_wp[COUT * 4];   // 64 outs x 16 dwords (as 4x int4) = 4 KB
    __shared__ float4 s_par[COUT];      // 1 KB

    int tid = threadIdx.x;              // 0..127
    // stage weights: 256 int4, two per thread
    s_wp[tid]       = ((const int4*)wp_g)[tid];
    s_wp[tid + 128] = ((const int4*)wp_g)[tid + 128];
    if (tid < COUT) s_par[tid] = params_g[tid];
    int izp_adj = izp_p[0] - 128;      // 0 for the reference inputs; exact otherwise
    __syncthreads();

    int t = blockIdx.x * 128 + tid;    // pixel index 0..524287
    int b = t >> 14;                   // / HW
    int p = t & (HW - 1);

    const int* xb = x + b * (CIN * HW) + p;

    // px[cg]: channel group cg = 4 channels packed as signed bytes (x-128)
    int px[16];
    #pragma unroll
    for (int cg = 0; cg < 16; ++cg) {
        int v0 = xb[(4 * cg + 0) * HW];
        int v1 = xb[(4 * cg + 1) * HW];
        int v2 = xb[(4 * cg + 2) * HW];
        int v3 = xb[(4 * cg + 3) * HW];
        // values are 0..255 in low byte; (x-128) as int8 == byte XOR 0x80
        px[cg] = (v0 | (v1 << 8) | (v2 << 16) | (v3 << 24)) ^ 0x80808080;
    }

    int* ob = out + b * (COUT * HW) + p;

    #pragma unroll 8
    for (int o = 0; o < COUT; ++o) {
        int4 w0 = s_wp[o * 4 + 0];
        int4 w1 = s_wp[o * 4 + 1];
        int4 w2 = s_wp[o * 4 + 2];
        int4 w3 = s_wp[o * 4 + 3];
        float4 pr = s_par[o];
        int wsum = __float_as_int(pr.z);
        int acc = -izp_adj * wsum;      // izp correction (0 here)

        acc = __builtin_amdgcn_sdot4(px[0],  w0.x, acc, false);
        acc = __builtin_amdgcn_sdot4(px[1],  w0.y, acc, false);
        acc = __builtin_amdgcn_sdot4(px[2],  w0.z, acc, false);
        acc = __builtin_amdgcn_sdot4(px[3],  w0.w, acc, false);
        acc = __builtin_amdgcn_sdot4(px[4],  w1.x, acc, false);
        acc = __builtin_amdgcn_sdot4(px[5],  w1.y, acc, false);
        acc = __builtin_amdgcn_sdot4(px[6],  w1.z, acc, false);
        acc = __builtin_amdgcn_sdot4(px[7],  w1.w, acc, false);
        acc = __builtin_amdgcn_sdot4(px[8],  w2.x, acc, false);
        acc = __builtin_amdgcn_sdot4(px[9],  w2.y, acc, false);
        acc = __builtin_amdgcn_sdot4(px[10], w2.z, acc, false);
        acc = __builtin_amdgcn_sdot4(px[11], w2.w, acc, false);
        acc = __builtin_amdgcn_sdot4(px[12], w3.x, acc, false);
        acc = __builtin_amdgcn_sdot4(px[13], w3.y, acc, false);
        acc = __builtin_amdgcn_sdot4(px[14], w3.z, acc, false);
        acc = __builtin_amdgcn_sdot4(px[15], w3.w, acc, false);

        float f = fmaf((float)acc, pr.x, pr.y);
        f = rintf(f);                         // v_rndne: round-half-even, matches jnp.round
        f = fminf(fmaxf(f, 0.0f), 255.0f);    // clamp to uint8 range
        __builtin_nontemporal_store((int)f, ob + o * HW);
    }
}

extern "C" void kernel_launch(void* const* d_in, const int* in_sizes, int n_in,
                              void* d_out, int out_size, void* d_ws, size_t ws_size,
                              hipStream_t stream) {
    const int*   x      = (const int*)d_in[0];     // [32,64,128,128] int32 (uint8 vals)
    const float* is_p   = (const float*)d_in[1];   // input_scale
    const int*   izp_p  = (const int*)d_in[2];     // input_zero_point
    const int*   w      = (const int*)d_in[3];     // [64,64,1,1] int32
    const float* wscale = (const float*)d_in[4];   // [64]
    const int*   wzp    = (const int*)d_in[5];     // [64]
    const float* bias   = (const float*)d_in[6];   // [64]
    const float* os_p   = (const float*)d_in[7];   // output_scale
    const int*   ozp_p  = (const int*)d_in[8];     // output_zero_point

    int* out = (int*)d_out;

    int*    wp     = (int*)d_ws;                       // 4096 B
    float4* params = (float4*)((char*)d_ws + 4096);    // 1024 B

    prep_kernel<<<1, 64, 0, stream>>>(w, wscale, wzp, bias, is_p, os_p, ozp_p, wp, params);

    // 524288 pixels / 1 per thread / 128 per block = 4096 blocks
    conv_kernel<<<4096, 128, 0, stream>>>(x, wp, params, izp_p, out);
}

// Round 7
// 253.396 us; speedup vs baseline: 1.1136x; 1.0058x over previous
//
#include <hip/hip_runtime.h>

// Problem constants (from reference): B=32, CIN=64, COUT=64, H=W=128, 1x1 conv
#define CIN   64
#define COUT  64
#define HW    16384          // 128*128
#define NPIX  (32 * HW)      // B * H * W = 524288

// ---------------------------------------------------------------------------
// Prep kernel: pack weights to int8 dwords + fold requant params.
// wp[o*16 + k] holds (w[o][4k..4k+3] - wzp[o]) as 4 signed bytes.
// params[o] = { scale_o, bias_o/os + ozp, as_float(sum_ci(w'-wzp)), 0 }
// ---------------------------------------------------------------------------
__global__ void prep_kernel(const int* __restrict__ w,
                            const float* __restrict__ wscale,
                            const int* __restrict__ wzp,
                            const float* __restrict__ bias,
                            const float* __restrict__ is_p,
                            const float* __restrict__ os_p,
                            const int* __restrict__ ozp_p,
                            int* __restrict__ wp,
                            float4* __restrict__ params) {
    int o = threadIdx.x;
    if (o >= COUT) return;
    int zp = wzp[o];
    int sum = 0;
    #pragma unroll
    for (int k = 0; k < 16; ++k) {
        int c0 = w[o * CIN + 4 * k + 0] - zp;
        int c1 = w[o * CIN + 4 * k + 1] - zp;
        int c2 = w[o * CIN + 4 * k + 2] - zp;
        int c3 = w[o * CIN + 4 * k + 3] - zp;
        sum += c0 + c1 + c2 + c3;
        wp[o * 16 + k] = (c0 & 0xff) | ((c1 & 0xff) << 8) |
                         ((c2 & 0xff) << 16) | ((c3 & 0xff) << 24);
    }
    float scale = is_p[0] * wscale[o] / os_p[0];
    float bterm = bias[o] / os_p[0] + (float)ozp_p[0];
    float4 pr;
    pr.x = scale;
    pr.y = bterm;
    pr.z = __int_as_float(sum);
    pr.w = 0.0f;
    params[o] = pr;
}

// ---------------------------------------------------------------------------
// Main kernel: ROUND-0's proven body (83.5 us best) with ONE variable
// changed: weights/params come from UNIFORM-indexed global loads instead
// of LDS staging. No __shared__, no __syncthreads.
//
// ROUND-6 POST-MORTEM: at VGPR=60/LDS=5KB, round-0's entire grid is
// resident (32 waves/CU) — TLP was never the lever. The stall is the
// per-o LDS round-trip: 5 broadcast ds_reads + lgkmcnt wait gating 16
// sdots, 320 LDS instrs/wave with exposed latency the 60-VGPR budget
// can't pipeline. Weights are wave-uniform -> belong in SGPRs: uniform
// address + no aliasing stores => compiler emits s_load_dwordx4 (K$-
// resident 4KB, scalar pipe runs parallel to VALU, zero VGPR cost, deep
// SGPR prefetch is cheap). v_dot4 legally takes 1 SGPR operand.
// VALIDITY CHECK: SGPR_Count must rise well above 32, else the loads
// stayed vector and the experiment is void.
// ---------------------------------------------------------------------------
__global__ __launch_bounds__(256) void conv_kernel(
    const int* __restrict__ x,
    const int* __restrict__ wp_g,
    const float4* __restrict__ params_g,
    const int* __restrict__ izp_p,
    int* __restrict__ out) {

    int tid = threadIdx.x;
    int izp_adj = izp_p[0] - 128;      // uniform -> s_load; 0 for reference inputs

    int t = blockIdx.x * 256 + tid;    // pixel index 0..524287
    int b = t >> 14;                   // / HW
    int p = t & (HW - 1);

    const int* xb = x + b * (CIN * HW) + p;

    // px[cg]: channel group cg = 4 channels packed as signed bytes (x-128)
    int px[16];
    #pragma unroll
    for (int cg = 0; cg < 16; ++cg) {
        int v0 = xb[(4 * cg + 0) * HW];
        int v1 = xb[(4 * cg + 1) * HW];
        int v2 = xb[(4 * cg + 2) * HW];
        int v3 = xb[(4 * cg + 3) * HW];
        // values are 0..255 in low byte; (x-128) as int8 == byte XOR 0x80
        px[cg] = (v0 | (v1 << 8) | (v2 << 16) | (v3 << 24)) ^ 0x80808080;
    }

    int* ob = out + b * (COUT * HW) + p;

    // o, and thus every weight/param address, is wave-uniform -> scalar loads.
    // unroll 4: ~80 SGPR-dwords of hoistable weight state, inside budget.
    #pragma unroll 4
    for (int o = 0; o < COUT; ++o) {
        const int4* wr = (const int4*)(wp_g + o * 16);
        int4 w0 = wr[0];
        int4 w1 = wr[1];
        int4 w2 = wr[2];
        int4 w3 = wr[3];
        float4 pr = params_g[o];
        int wsum = __float_as_int(pr.z);
        int acc = -izp_adj * wsum;      // izp correction (0 here)

        acc = __builtin_amdgcn_sdot4(px[0],  w0.x, acc, false);
        acc = __builtin_amdgcn_sdot4(px[1],  w0.y, acc, false);
        acc = __builtin_amdgcn_sdot4(px[2],  w0.z, acc, false);
        acc = __builtin_amdgcn_sdot4(px[3],  w0.w, acc, false);
        acc = __builtin_amdgcn_sdot4(px[4],  w1.x, acc, false);
        acc = __builtin_amdgcn_sdot4(px[5],  w1.y, acc, false);
        acc = __builtin_amdgcn_sdot4(px[6],  w1.z, acc, false);
        acc = __builtin_amdgcn_sdot4(px[7],  w1.w, acc, false);
        acc = __builtin_amdgcn_sdot4(px[8],  w2.x, acc, false);
        acc = __builtin_amdgcn_sdot4(px[9],  w2.y, acc, false);
        acc = __builtin_amdgcn_sdot4(px[10], w2.z, acc, false);
        acc = __builtin_amdgcn_sdot4(px[11], w2.w, acc, false);
        acc = __builtin_amdgcn_sdot4(px[12], w3.x, acc, false);
        acc = __builtin_amdgcn_sdot4(px[13], w3.y, acc, false);
        acc = __builtin_amdgcn_sdot4(px[14], w3.z, acc, false);
        acc = __builtin_amdgcn_sdot4(px[15], w3.w, acc, false);

        float f = fmaf((float)acc, pr.x, pr.y);
        f = rintf(f);                         // v_rndne: round-half-even, matches jnp.round
        f = fminf(fmaxf(f, 0.0f), 255.0f);    // clamp to uint8 range
        __builtin_nontemporal_store((int)f, ob + o * HW);
    }
}

extern "C" void kernel_launch(void* const* d_in, const int* in_sizes, int n_in,
                              void* d_out, int out_size, void* d_ws, size_t ws_size,
                              hipStream_t stream) {
    const int*   x      = (const int*)d_in[0];     // [32,64,128,128] int32 (uint8 vals)
    const float* is_p   = (const float*)d_in[1];   // input_scale
    const int*   izp_p  = (const int*)d_in[2];     // input_zero_point
    const int*   w      = (const int*)d_in[3];     // [64,64,1,1] int32
    const float* wscale = (const float*)d_in[4];   // [64]
    const int*   wzp    = (const int*)d_in[5];     // [64]
    const float* bias   = (const float*)d_in[6];   // [64]
    const float* os_p   = (const float*)d_in[7];   // output_scale
    const int*   ozp_p  = (const int*)d_in[8];     // output_zero_point

    int* out = (int*)d_out;

    int*    wp     = (int*)d_ws;                       // 4096 B
    float4* params = (float4*)((char*)d_ws + 4096);    // 1024 B

    prep_kernel<<<1, 64, 0, stream>>>(w, wscale, wzp, bias, is_p, os_p, ozp_p, wp, params);

    // 524288 pixels / 1 per thread / 256 per block = 2048 blocks
    conv_kernel<<<2048, 256, 0, stream>>>(x, wp, params, izp_p, out);
}